// Round 1
// baseline (460.542 us; speedup 1.0000x reference)
//
#include <hip/hip_runtime.h>

// ---------------------------------------------------------------------------
// CondConv2d  (B=32, C=256, H=W=56, E=4, O=256, K=3, stride=1, pad=1)
//
// Pipeline:
//   1) init_ws        : zero pooled[32][256] + zero borders of xp
//   2) transform_pool : x[B,C,H,W] f32 -> xp[B,58,58,C] bf16 (channels-last,
//                       zero-padded), fused global-avg-pool partials (atomic)
//   3) routing_kernel : pooled -> relu(fc1) -> softmax(fc2) -> routing[32][4]
//   4) combine_kernel : wcomb[b][o][k] bf16, k = r*256 + c  (r = 3*ki+kj)
//   5) conv_gemm      : per-sample implicit GEMM  out[o][p] = W[o][k]*im2col[p][k]
//                       128x128 tile, BK=32, mfma_f32_16x16x32_bf16,
//                       global_load_lds(16B) staging for both operands.
// ---------------------------------------------------------------------------

#define B_  32
#define C_  256
#define H_  56
#define W_  56
#define HW_ 3136         // 56*56
#define E_  4
#define O_  256
#define HID_ 64
#define HP_ 58           // padded
#define PHW_ 3364        // 58*58
#define KK_ 2304         // C*9, GEMM K

typedef __attribute__((ext_vector_type(8))) short bf16x8;
typedef __attribute__((ext_vector_type(4))) float f32x4;

__device__ __forceinline__ unsigned short f2bf(float f) {
    unsigned int u = __float_as_uint(f);
    u = (u + 0x7FFFu + ((u >> 16) & 1u)) >> 16;   // round-to-nearest-even
    return (unsigned short)u;
}

__device__ __forceinline__ void load_lds16(const void* g, void* l) {
    // global -> LDS DMA, 16 B per lane; LDS dest = wave-uniform base + lane*16
    __builtin_amdgcn_global_load_lds(
        (__attribute__((address_space(1))) unsigned int*)(unsigned long long)(const char*)g,
        (__attribute__((address_space(3))) unsigned int*)l,
        16, 0, 0);
}

// --------------------------- 1) init workspace ------------------------------
__global__ void init_ws(unsigned short* __restrict__ xp, float* __restrict__ pooled) {
    const int b = blockIdx.x;
    const int t = threadIdx.x;
    pooled[b * C_ + t] = 0.0f;
    unsigned int* base = (unsigned int*)(xp + (size_t)b * PHW_ * C_);
    // rows hp=0 and hp=57 : 58*256 ushorts = 58*128 uints each
    for (int i = t; i < HP_ * 128; i += 256) {
        base[i] = 0u;                                  // hp = 0
        base[57 * HP_ * 128 + i] = 0u;                 // hp = 57
    }
    // cols wp=0 and wp=57 for hp=1..56 : 128 uints per pixel
    for (int i = t; i < 56 * 128; i += 256) {
        int hp = 1 + (i >> 7);
        int cc = i & 127;
        base[(hp * HP_ + 0) * 128 + cc]  = 0u;
        base[(hp * HP_ + 57) * 128 + cc] = 0u;
    }
}

// ------------------ 2) NCHW f32 -> padded NHWC bf16 + pool ------------------
__global__ void transform_pool(const float* __restrict__ x,
                               unsigned short* __restrict__ xp,
                               float* __restrict__ pooled) {
    const int h = blockIdx.x;      // 0..55
    const int b = blockIdx.y;      // 0..31
    const int c = threadIdx.x;     // 0..255
    const float* row = x + ((size_t)(b * C_ + c) * H_ + h) * W_;
    unsigned short* orow = xp + ((size_t)(b * HP_ + h + 1) * HP_ + 1) * C_ + c;
    float s = 0.0f;
#pragma unroll
    for (int w = 0; w < W_; w += 4) {
        float4 v = *(const float4*)(row + w);
        s += v.x + v.y + v.z + v.w;
        orow[(size_t)(w + 0) * C_] = f2bf(v.x);
        orow[(size_t)(w + 1) * C_] = f2bf(v.y);
        orow[(size_t)(w + 2) * C_] = f2bf(v.z);
        orow[(size_t)(w + 3) * C_] = f2bf(v.w);
    }
    atomicAdd(&pooled[b * C_ + c], s);
}

// ------------------------------ 3) routing ----------------------------------
__global__ void routing_kernel(const float* __restrict__ pooled,
                               const float* __restrict__ rw1,
                               const float* __restrict__ rb1,
                               const float* __restrict__ rw2,
                               const float* __restrict__ rb2,
                               float* __restrict__ routing) {
    const int b = blockIdx.x;
    const int t = threadIdx.x;
    __shared__ float pl[C_];
    __shared__ float part[256];
    __shared__ float hb[HID_];
    __shared__ float lg[E_];
    pl[t] = pooled[b * C_ + t] * (1.0f / (float)HW_);
    __syncthreads();
    const int j = t >> 2, seg = t & 3;
    {
        const float* w = rw1 + j * C_ + seg * 64;
        const float* p = pl + seg * 64;
        float s = 0.0f;
#pragma unroll 8
        for (int cc = 0; cc < 64; ++cc) s += p[cc] * w[cc];
        part[t] = s;
    }
    __syncthreads();
    if (seg == 0) {
        float s = part[t] + part[t + 1] + part[t + 2] + part[t + 3] + rb1[j];
        hb[j] = fmaxf(s, 0.0f);
    }
    __syncthreads();
    if (t < E_) {
        float s = rb2[t];
        for (int jj = 0; jj < HID_; ++jj) s += hb[jj] * rw2[t * HID_ + jj];
        lg[t] = s;
    }
    __syncthreads();
    if (t == 0) {
        float mx = fmaxf(fmaxf(lg[0], lg[1]), fmaxf(lg[2], lg[3]));
        float e0 = expf(lg[0] - mx), e1 = expf(lg[1] - mx);
        float e2 = expf(lg[2] - mx), e3 = expf(lg[3] - mx);
        float inv = 1.0f / (e0 + e1 + e2 + e3);
        routing[b * E_ + 0] = e0 * inv;
        routing[b * E_ + 1] = e1 * inv;
        routing[b * E_ + 2] = e2 * inv;
        routing[b * E_ + 3] = e3 * inv;
    }
}

// --------------------- 4) combined weights, k = r*256+c ---------------------
__global__ void combine_kernel(const float* __restrict__ experts,
                               const float* __restrict__ routing,
                               unsigned short* __restrict__ wcomb) {
    const int o = blockIdx.x;      // 0..255
    const int b = blockIdx.y;      // 0..31
    const int c = threadIdx.x;     // 0..255
    float acc[9];
#pragma unroll
    for (int r = 0; r < 9; ++r) acc[r] = 0.0f;
#pragma unroll
    for (int e = 0; e < E_; ++e) {
        const float re = routing[b * E_ + e];
        const float* ep = experts + ((size_t)(e * O_ + o) * C_ + c) * 9;
        float4 v0 = *(const float4*)(ep + 0);
        float4 v1 = *(const float4*)(ep + 4);
        float v8 = ep[8];
        acc[0] += re * v0.x; acc[1] += re * v0.y; acc[2] += re * v0.z; acc[3] += re * v0.w;
        acc[4] += re * v1.x; acc[5] += re * v1.y; acc[6] += re * v1.z; acc[7] += re * v1.w;
        acc[8] += re * v8;
    }
    unsigned short* wp = wcomb + (size_t)(b * O_ + o) * KK_ + c;
#pragma unroll
    for (int r = 0; r < 9; ++r) wp[(size_t)r * C_] = f2bf(acc[r]);
}

// --------------------------- 5) implicit-GEMM conv --------------------------
// out[b][o][p] = sum_k wcomb[b][o][k] * xp[b][h(p)+di][w(p)+dj][c]
//   k = r*256+c, r = di*3+dj  -> each BK=32 chunk has uniform (di,dj), c-run of 32
__global__ __launch_bounds__(256) void conv_gemm(const unsigned short* __restrict__ xp,
                                                 const unsigned short* __restrict__ wcomb,
                                                 float* __restrict__ out) {
    __shared__ alignas(16) unsigned short Alds[128 * 32];  // [o_row][k32]
    __shared__ alignas(16) unsigned short Blds[128 * 32];  // [pix_row][k32]

    const int tid  = threadIdx.x;
    const int lane = tid & 63;
    const int wid  = tid >> 6;            // 0..3
    const int b  = blockIdx.z;
    const int o0 = blockIdx.y * 128;
    const int n0 = blockIdx.x * 128;

    // ---- staging setup: each wave stages 2x16 rows of A and of B ----
    const int skq = lane & 3;             // 16B chunk within a 64B row
    const unsigned short* asrc[2];
    const unsigned short* bsrc[2];
    unsigned short* aldst[2];
    unsigned short* bldst[2];
#pragma unroll
    for (int iss = 0; iss < 2; ++iss) {
        const int row = wid * 32 + iss * 16 + (lane >> 2);
        asrc[iss] = wcomb + (size_t)(b * O_ + o0 + row) * KK_ + skq * 8;
        int p = n0 + row; if (p > HW_ - 1) p = HW_ - 1;    // clamp partial N tile
        bsrc[iss] = xp + ((size_t)b * PHW_ + (p / W_) * HP_ + (p % W_)) * C_ + skq * 8;
        aldst[iss] = (unsigned short*)Alds + (wid * 32 + iss * 16) * 32;
        bldst[iss] = (unsigned short*)Blds + (wid * 32 + iss * 16) * 32;
    }

    f32x4 acc[4][4];
#pragma unroll
    for (int i = 0; i < 4; ++i)
#pragma unroll
        for (int j = 0; j < 4; ++j) acc[i][j] = (f32x4){0.f, 0.f, 0.f, 0.f};

    // fragment read addresses (A[m][k] / B[n][k], k-contiguous per lane)
    const int fm = lane & 15;             // m (A) / n (B)
    const int fq = lane >> 4;             // k quad: k = fq*8 + j
    const int wm = wid >> 1, wn = wid & 1;
    const unsigned short* ard = (const unsigned short*)Alds + (wm * 64 + fm) * 32 + fq * 8;
    const unsigned short* brd = (const unsigned short*)Blds + (wn * 64 + fm) * 32 + fq * 8;

    for (int kc = 0; kc < 72; ++kc) {
        const int r   = kc >> 3;                         // 0..8 = di*3+dj
        const int duA = kc * 32;                         // elements
        const int duB = ((r / 3) * HP_ + (r % 3)) * C_ + (kc & 7) * 32;
        __syncthreads();                                 // previous reads done
#pragma unroll
        for (int iss = 0; iss < 2; ++iss) {
            load_lds16(asrc[iss] + duA, aldst[iss]);
            load_lds16(bsrc[iss] + duB, bldst[iss]);
        }
        __syncthreads();                                 // staging visible
        bf16x8 af[4], bv[4];
#pragma unroll
        for (int mi = 0; mi < 4; ++mi) af[mi] = *(const bf16x8*)(ard + mi * 16 * 32);
#pragma unroll
        for (int ni = 0; ni < 4; ++ni) bv[ni] = *(const bf16x8*)(brd + ni * 16 * 32);
#pragma unroll
        for (int mi = 0; mi < 4; ++mi)
#pragma unroll
            for (int ni = 0; ni < 4; ++ni)
                acc[mi][ni] = __builtin_amdgcn_mfma_f32_16x16x32_bf16(
                    af[mi], bv[ni], acc[mi][ni], 0, 0, 0);
    }

    // ---- epilogue: D layout col(n)=lane&15, row(m)=(lane>>4)*4+reg ----
#pragma unroll
    for (int ni = 0; ni < 4; ++ni) {
        const int n = n0 + wn * 64 + ni * 16 + fm;
        if (n >= HW_) continue;
#pragma unroll
        for (int mi = 0; mi < 4; ++mi) {
            const int m = o0 + wm * 64 + mi * 16 + fq * 4;
            float* po = out + (size_t)(b * O_ + m) * HW_ + n;
#pragma unroll
            for (int rg = 0; rg < 4; ++rg) po[(size_t)rg * HW_] = acc[mi][ni][rg];
        }
    }
}

// ---------------------------------------------------------------------------
extern "C" void kernel_launch(void* const* d_in, const int* in_sizes, int n_in,
                              void* d_out, int out_size, void* d_ws, size_t ws_size,
                              hipStream_t stream) {
    const float* x       = (const float*)d_in[0];
    const float* experts = (const float*)d_in[1];
    const float* rw1     = (const float*)d_in[2];
    const float* rb1     = (const float*)d_in[3];
    const float* rw2     = (const float*)d_in[4];
    const float* rb2     = (const float*)d_in[5];
    float* out = (float*)d_out;

    // workspace layout (bytes)
    const size_t XP_OFF = 0;                                   // 32*3364*256*2 = 55,115,776
    const size_t WC_OFF = 55115776;                            // 32*256*2304*2 = 37,748,736
    const size_t PL_OFF = WC_OFF + 37748736;                   // 32*256*4      = 32,768
    const size_t RT_OFF = PL_OFF + 32768;                      // 32*4*4        = 512
    unsigned short* xp    = (unsigned short*)((char*)d_ws + XP_OFF);
    unsigned short* wcomb = (unsigned short*)((char*)d_ws + WC_OFF);
    float* pooled  = (float*)((char*)d_ws + PL_OFF);
    float* routing = (float*)((char*)d_ws + RT_OFF);

    init_ws<<<dim3(B_), dim3(256), 0, stream>>>(xp, pooled);
    transform_pool<<<dim3(H_, B_), dim3(256), 0, stream>>>(x, xp, pooled);
    routing_kernel<<<dim3(B_), dim3(256), 0, stream>>>(pooled, rw1, rb1, rw2, rb2, routing);
    combine_kernel<<<dim3(O_, B_), dim3(256), 0, stream>>>(experts, routing, wcomb);
    conv_gemm<<<dim3(25, 2, B_), dim3(256), 0, stream>>>(xp, wcomb, out);
}

// Round 2
// 378.481 us; speedup vs baseline: 1.2168x; 1.2168x over previous
//
#include <hip/hip_runtime.h>

// ---------------------------------------------------------------------------
// CondConv2d  (B=32, C=256, H=W=56, E=4, O=256, K=3, stride=1, pad=1)
//
//   1) init_ws        : zero pooled + zero borders of xp
//   2) transform_pool : x[B,C,H,W] f32 -> xp[B,58,58,C] bf16 via LDS transpose
//                       (coalesced reads), fused avg-pool partials
//   3) routing_kernel : pooled -> relu(fc1) -> softmax(fc2) -> routing[32][4]
//   4) combine_kernel : experts read ONCE; wcomb[b][o][k] bf16, k = r*256+c
//   5) conv_gemm      : implicit GEMM, 128x128 tile, BK=64, XOR-swizzled LDS
//                       (conflict-free ds_read_b128), XCD-clustered grid.
// ---------------------------------------------------------------------------

#define B_  32
#define C_  256
#define H_  56
#define W_  56
#define HW_ 3136
#define E_  4
#define O_  256
#define HID_ 64
#define HP_ 58
#define PHW_ 3364
#define KK_ 2304

typedef __attribute__((ext_vector_type(8))) short bf16x8;
typedef __attribute__((ext_vector_type(4))) float f32x4;

__device__ __forceinline__ unsigned short f2bf(float f) {
    unsigned int u = __float_as_uint(f);
    u = (u + 0x7FFFu + ((u >> 16) & 1u)) >> 16;   // round-to-nearest-even
    return (unsigned short)u;
}

__device__ __forceinline__ void load_lds16(const void* g, void* l) {
    // global -> LDS DMA, 16 B per lane; LDS dest = wave-uniform base + lane*16
    __builtin_amdgcn_global_load_lds(
        (__attribute__((address_space(1))) unsigned int*)(unsigned long long)(const char*)g,
        (__attribute__((address_space(3))) unsigned int*)l,
        16, 0, 0);
}

// --------------------------- 1) init workspace ------------------------------
__global__ void init_ws(unsigned short* __restrict__ xp, float* __restrict__ pooled) {
    const int b = blockIdx.x;
    const int t = threadIdx.x;
    pooled[b * C_ + t] = 0.0f;
    unsigned int* base = (unsigned int*)(xp + (size_t)b * PHW_ * C_);
    for (int i = t; i < HP_ * 128; i += 256) {
        base[i] = 0u;                                  // hp = 0
        base[57 * HP_ * 128 + i] = 0u;                 // hp = 57
    }
    for (int i = t; i < 56 * 128; i += 256) {
        int hp = 1 + (i >> 7);
        int cc = i & 127;
        base[(hp * HP_ + 0) * 128 + cc]  = 0u;
        base[(hp * HP_ + 57) * 128 + cc] = 0u;
    }
}

// ------------------ 2) NCHW f32 -> padded NHWC bf16 + pool ------------------
// grid (56, 2, 32), 256 threads. LDS transpose for coalesced global reads.
__global__ void transform_pool(const float* __restrict__ x,
                               unsigned short* __restrict__ xp,
                               float* __restrict__ pooled) {
    const int h    = blockIdx.x;       // 0..55
    const int half = blockIdx.y;       // 0..1  (channel half)
    const int b    = blockIdx.z;
    const int t    = threadIdx.x;
    const int c0   = half * 128;
    __shared__ float tile[128 * 57];   // [c][w], pad 57

    const float* src = x + ((size_t)(b * C_ + c0) * H_ + h) * W_;
#pragma unroll
    for (int i = t; i < 128 * 14; i += 256) {
        const int c  = i / 14;
        const int w4 = (i % 14) * 4;
        float4 v = *(const float4*)(src + (size_t)c * (H_ * W_) + w4);
        tile[c * 57 + w4 + 0] = v.x;
        tile[c * 57 + w4 + 1] = v.y;
        tile[c * 57 + w4 + 2] = v.z;
        tile[c * 57 + w4 + 3] = v.w;
    }
    __syncthreads();

    const int cu = t & 63;             // channel-pair index (2 bf16 -> 1 uint)
    const int ws = t >> 6;             // w segment 0..3 (14 each)
    float s0 = 0.f, s1 = 0.f;
    unsigned int* ob = (unsigned int*)xp
        + ((size_t)(b * HP_ + h + 1) * HP_ + 1) * (C_ / 2) + (c0 >> 1) + cu;
#pragma unroll
    for (int w = ws * 14; w < ws * 14 + 14; ++w) {
        float f0 = tile[(2 * cu + 0) * 57 + w];
        float f1 = tile[(2 * cu + 1) * 57 + w];
        s0 += f0; s1 += f1;
        ob[(size_t)w * (C_ / 2)] =
            (unsigned int)f2bf(f0) | ((unsigned int)f2bf(f1) << 16);
    }
    atomicAdd(&pooled[b * C_ + c0 + 2 * cu + 0], s0);
    atomicAdd(&pooled[b * C_ + c0 + 2 * cu + 1], s1);
}

// ------------------------------ 3) routing ----------------------------------
__global__ void routing_kernel(const float* __restrict__ pooled,
                               const float* __restrict__ rw1,
                               const float* __restrict__ rb1,
                               const float* __restrict__ rw2,
                               const float* __restrict__ rb2,
                               float* __restrict__ routing) {
    const int b = blockIdx.x;
    const int t = threadIdx.x;
    __shared__ float pl[C_];
    __shared__ float part[256];
    __shared__ float hb[HID_];
    __shared__ float lg[E_];
    pl[t] = pooled[b * C_ + t] * (1.0f / (float)HW_);
    __syncthreads();
    const int j = t >> 2, seg = t & 3;
    {
        const float* w = rw1 + j * C_ + seg * 64;
        const float* p = pl + seg * 64;
        float s = 0.0f;
#pragma unroll 8
        for (int cc = 0; cc < 64; ++cc) s += p[cc] * w[cc];
        part[t] = s;
    }
    __syncthreads();
    if (seg == 0) {
        float s = part[t] + part[t + 1] + part[t + 2] + part[t + 3] + rb1[j];
        hb[j] = fmaxf(s, 0.0f);
    }
    __syncthreads();
    if (t < E_) {
        float s = rb2[t];
        for (int jj = 0; jj < HID_; ++jj) s += hb[jj] * rw2[t * HID_ + jj];
        lg[t] = s;
    }
    __syncthreads();
    if (t == 0) {
        float mx = fmaxf(fmaxf(lg[0], lg[1]), fmaxf(lg[2], lg[3]));
        float e0 = expf(lg[0] - mx), e1 = expf(lg[1] - mx);
        float e2 = expf(lg[2] - mx), e3 = expf(lg[3] - mx);
        float inv = 1.0f / (e0 + e1 + e2 + e3);
        routing[b * E_ + 0] = e0 * inv;
        routing[b * E_ + 1] = e1 * inv;
        routing[b * E_ + 2] = e2 * inv;
        routing[b * E_ + 3] = e3 * inv;
    }
}

// --------------------- 4) combined weights, k = r*256+c ---------------------
// grid (256), 256 threads: experts read once, loop over b in registers.
__global__ void combine_kernel(const float* __restrict__ experts,
                               const float* __restrict__ routing,
                               unsigned short* __restrict__ wcomb) {
    const int o = blockIdx.x;
    const int c = threadIdx.x;
    __shared__ float rt[B_ * E_];
    if (c < B_ * E_) rt[c] = routing[c];
    __syncthreads();

    float w[E_][9];
#pragma unroll
    for (int e = 0; e < E_; ++e) {
        const float* ep = experts + ((size_t)(e * O_ + o) * C_ + c) * 9;
        float4 v0 = *(const float4*)(ep + 0);
        float4 v1 = *(const float4*)(ep + 4);
        w[e][0] = v0.x; w[e][1] = v0.y; w[e][2] = v0.z; w[e][3] = v0.w;
        w[e][4] = v1.x; w[e][5] = v1.y; w[e][6] = v1.z; w[e][7] = v1.w;
        w[e][8] = ep[8];
    }
    for (int b = 0; b < B_; ++b) {
        const float r0 = rt[b * 4 + 0], r1 = rt[b * 4 + 1];
        const float r2 = rt[b * 4 + 2], r3 = rt[b * 4 + 3];
        unsigned short* wp = wcomb + (size_t)(b * O_ + o) * KK_ + c;
#pragma unroll
        for (int k = 0; k < 9; ++k) {
            float a = r0 * w[0][k] + r1 * w[1][k] + r2 * w[2][k] + r3 * w[3][k];
            wp[(size_t)k * C_] = f2bf(a);
        }
    }
}

// --------------------------- 5) implicit-GEMM conv --------------------------
// BK=64, XOR-swizzled LDS: slot s of row R holds global 16B-chunk s^(R&7).
// Grid = 1600 linear, XCD-clustered: sample b -> id%8 (one XCD per sample).
__global__ __launch_bounds__(256) void conv_gemm(const unsigned short* __restrict__ xp,
                                                 const unsigned short* __restrict__ wcomb,
                                                 float* __restrict__ out) {
    __shared__ alignas(16) unsigned short Alds[128 * 64];  // 16 KB
    __shared__ alignas(16) unsigned short Blds[128 * 64];  // 16 KB

    const int tid  = threadIdx.x;
    const int lane = tid & 63;
    const int wid  = tid >> 6;

    // XCD-cluster decode: all 50 tiles of sample b land on XCD b%8
    const int id = blockIdx.x;
    const int b  = (id >> 3) / 50 * 8 + (id & 7);
    const int t  = (id >> 3) % 50;
    const int o0 = (t & 1) * 128;
    const int n0 = (t >> 1) * 128;

    const int qg = (lane & 7) ^ ((lane >> 3) & 7);   // swizzled global chunk

    // staging: each wave stages 32 rows of A and 32 of B (4 DMAs each, 8 rows/DMA)
    const unsigned short* aptr = wcomb
        + (size_t)(b * O_ + o0 + wid * 32 + (lane >> 3)) * KK_ + qg * 8;
    const unsigned short* bptr = xp + (size_t)b * PHW_ * C_ + qg * 8;
    unsigned int boff[4];
#pragma unroll
    for (int iss = 0; iss < 4; ++iss) {
        int p = n0 + wid * 32 + iss * 8 + (lane >> 3);
        if (p > HW_ - 1) p = HW_ - 1;                // clamp partial N tile
        boff[iss] = (unsigned int)((p / W_) * HP_ + (p % W_)) * C_;
    }
    unsigned short* aldst = (unsigned short*)Alds + (wid * 32) * 64;
    unsigned short* bldst = (unsigned short*)Blds + (wid * 32) * 64;

    f32x4 acc[4][4];
#pragma unroll
    for (int i = 0; i < 4; ++i)
#pragma unroll
        for (int j = 0; j < 4; ++j) acc[i][j] = (f32x4){0.f, 0.f, 0.f, 0.f};

    // fragment readers (un-swizzle): chunk q=ks*4+fq lives at slot q^(fm&7)
    const int fm = lane & 15;
    const int fq = lane >> 4;
    const int wm = wid >> 1, wn = wid & 1;
    const int colk0 = ((0 + fq) ^ (fm & 7)) * 8;
    const int colk1 = ((4 + fq) ^ (fm & 7)) * 8;
    const unsigned short* ardb = (const unsigned short*)Alds + (wm * 64 + fm) * 64;
    const unsigned short* brdb = (const unsigned short*)Blds + (wn * 64 + fm) * 64;

    for (int kc = 0; kc < 36; ++kc) {
        const int r   = kc >> 2;                     // 0..8 = di*3+dj
        const int duA = kc * 64;
        const int duB = ((r / 3) * HP_ + (r % 3)) * C_ + (kc & 3) * 64;
        __syncthreads();                             // prev reads done
#pragma unroll
        for (int iss = 0; iss < 4; ++iss) {
            load_lds16(aptr + (size_t)iss * (8 * KK_) + duA, aldst + iss * (8 * 64));
            load_lds16(bptr + boff[iss] + duB,              bldst + iss * (8 * 64));
        }
        __syncthreads();                             // staging visible
#pragma unroll
        for (int ks = 0; ks < 2; ++ks) {
            const int col = ks ? colk1 : colk0;
            bf16x8 af[4], bv[4];
#pragma unroll
            for (int mi = 0; mi < 4; ++mi) af[mi] = *(const bf16x8*)(ardb + mi * (16 * 64) + col);
#pragma unroll
            for (int ni = 0; ni < 4; ++ni) bv[ni] = *(const bf16x8*)(brdb + ni * (16 * 64) + col);
#pragma unroll
            for (int mi = 0; mi < 4; ++mi)
#pragma unroll
                for (int ni = 0; ni < 4; ++ni)
                    acc[mi][ni] = __builtin_amdgcn_mfma_f32_16x16x32_bf16(
                        af[mi], bv[ni], acc[mi][ni], 0, 0, 0);
        }
    }

    // epilogue: D layout col(n)=lane&15, row(m)=(lane>>4)*4+reg
#pragma unroll
    for (int ni = 0; ni < 4; ++ni) {
        const int n = n0 + wn * 64 + ni * 16 + fm;
        if (n >= HW_) continue;
#pragma unroll
        for (int mi = 0; mi < 4; ++mi) {
            const int m = o0 + wm * 64 + mi * 16 + fq * 4;
            float* po = out + (size_t)(b * O_ + m) * HW_ + n;
#pragma unroll
            for (int rg = 0; rg < 4; ++rg) po[(size_t)rg * HW_] = acc[mi][ni][rg];
        }
    }
}

// ---------------------------------------------------------------------------
extern "C" void kernel_launch(void* const* d_in, const int* in_sizes, int n_in,
                              void* d_out, int out_size, void* d_ws, size_t ws_size,
                              hipStream_t stream) {
    const float* x       = (const float*)d_in[0];
    const float* experts = (const float*)d_in[1];
    const float* rw1     = (const float*)d_in[2];
    const float* rb1     = (const float*)d_in[3];
    const float* rw2     = (const float*)d_in[4];
    const float* rb2     = (const float*)d_in[5];
    float* out = (float*)d_out;

    const size_t XP_OFF = 0;                                   // 55,115,776 B
    const size_t WC_OFF = 55115776;                            // 37,748,736 B
    const size_t PL_OFF = WC_OFF + 37748736;
    const size_t RT_OFF = PL_OFF + 32768;
    unsigned short* xp    = (unsigned short*)((char*)d_ws + XP_OFF);
    unsigned short* wcomb = (unsigned short*)((char*)d_ws + WC_OFF);
    float* pooled  = (float*)((char*)d_ws + PL_OFF);
    float* routing = (float*)((char*)d_ws + RT_OFF);

    init_ws<<<dim3(B_), dim3(256), 0, stream>>>(xp, pooled);
    transform_pool<<<dim3(H_, 2, B_), dim3(256), 0, stream>>>(x, xp, pooled);
    routing_kernel<<<dim3(B_), dim3(256), 0, stream>>>(pooled, rw1, rb1, rw2, rb2, routing);
    combine_kernel<<<dim3(O_), dim3(256), 0, stream>>>(experts, routing, wcomb);
    conv_gemm<<<dim3(1600), dim3(256), 0, stream>>>(xp, wcomb, out);
}

// Round 3
// 323.345 us; speedup vs baseline: 1.4243x; 1.1705x over previous
//
#include <hip/hip_runtime.h>

// ---------------------------------------------------------------------------
// CondConv2d  (B=32, C=256, H=W=56, E=4, O=256, K=3, stride=1, pad=1)
//
//   1) transform_pool : x[B,C,H,W] f32 -> xp[B,58,58,C] bf16 via LDS transpose,
//                       fused border zeroing + per-(b,c,h) pool partials (no atomics)
//   2) routing_kernel : reduce pp -> relu(fc1) -> softmax(fc2) -> routing[32][4]
//   3) combine_kernel : grid (256,8); experts in regs; LDS-staged uint4 stores
//   4) conv_gemm      : implicit GEMM, 128x128, BK=64, XOR-swizzled LDS,
//                       XCD-clustered grid, __launch_bounds__(256,4)
// ---------------------------------------------------------------------------

#define B_  32
#define C_  256
#define H_  56
#define W_  56
#define HW_ 3136
#define E_  4
#define O_  256
#define HID_ 64
#define HP_ 58
#define PHW_ 3364
#define KK_ 2304

typedef __attribute__((ext_vector_type(8))) short bf16x8;
typedef __attribute__((ext_vector_type(4))) float f32x4;

__device__ __forceinline__ unsigned short f2bf(float f) {
    unsigned int u = __float_as_uint(f);
    u = (u + 0x7FFFu + ((u >> 16) & 1u)) >> 16;   // round-to-nearest-even
    return (unsigned short)u;
}

__device__ __forceinline__ void load_lds16(const void* g, void* l) {
    // global -> LDS DMA, 16 B per lane; LDS dest = wave-uniform base + lane*16
    __builtin_amdgcn_global_load_lds(
        (__attribute__((address_space(1))) unsigned int*)(unsigned long long)(const char*)g,
        (__attribute__((address_space(3))) unsigned int*)l,
        16, 0, 0);
}

// ---------- 1) NCHW f32 -> padded NHWC bf16 + pool partials + borders -------
// grid (56, 2, 32), 256 threads.
__global__ void transform_pool(const float* __restrict__ x,
                               unsigned short* __restrict__ xp,
                               float* __restrict__ pp) {
    const int h    = blockIdx.x;       // 0..55
    const int half = blockIdx.y;       // channel half
    const int b    = blockIdx.z;
    const int t    = threadIdx.x;
    const int c0   = half * 128;
    __shared__ float tile[128 * 57];
    __shared__ float part[4][128];

    const float* src = x + ((size_t)(b * C_ + c0) * H_ + h) * W_;
#pragma unroll
    for (int i = t; i < 128 * 14; i += 256) {
        const int c  = i / 14;
        const int w4 = (i % 14) * 4;
        float4 v = *(const float4*)(src + (size_t)c * (H_ * W_) + w4);
        tile[c * 57 + w4 + 0] = v.x;
        tile[c * 57 + w4 + 1] = v.y;
        tile[c * 57 + w4 + 2] = v.z;
        tile[c * 57 + w4 + 3] = v.w;
    }

    // border zeroing (fused; xp is poison-initialized every launch)
    unsigned int* ubase = (unsigned int*)(xp + (size_t)b * PHW_ * C_);
    {
        const int hp = h + 1;
        if (t < 128) {                 // cols wp=0,57 for this row, this half
            const int col = (t >> 6) ? 57 : 0;
            const int cu  = t & 63;
            ubase[((size_t)hp * HP_ + col) * 128 + half * 64 + cu] = 0u;
        }
        if (h == 0) {                  // rows hp=0 and hp=57, this half
            for (int i = t; i < HP_ * 64; i += 256) {
                const int pix = i >> 6, cu = i & 63;
                ubase[(size_t)pix * 128 + half * 64 + cu] = 0u;
                ubase[((size_t)57 * HP_ + pix) * 128 + half * 64 + cu] = 0u;
            }
        }
    }
    __syncthreads();

    const int cu = t & 63;             // channel-pair
    const int ws = t >> 6;             // w segment (14 each)
    float s0 = 0.f, s1 = 0.f;
    unsigned int* ob = (unsigned int*)xp
        + ((size_t)(b * HP_ + h + 1) * HP_ + 1) * (C_ / 2) + (c0 >> 1) + cu;
#pragma unroll
    for (int w = ws * 14; w < ws * 14 + 14; ++w) {
        float f0 = tile[(2 * cu + 0) * 57 + w];
        float f1 = tile[(2 * cu + 1) * 57 + w];
        s0 += f0; s1 += f1;
        ob[(size_t)w * (C_ / 2)] =
            (unsigned int)f2bf(f0) | ((unsigned int)f2bf(f1) << 16);
    }
    part[ws][2 * cu + 0] = s0;
    part[ws][2 * cu + 1] = s1;
    __syncthreads();
    if (t < 128) {
        float v = part[0][t] + part[1][t] + part[2][t] + part[3][t];
        pp[((size_t)(b * C_ + c0 + t)) * 56 + h] = v;
    }
}

// ------------------------------ 2) routing ----------------------------------
__global__ void routing_kernel(const float* __restrict__ pp,
                               const float* __restrict__ rw1,
                               const float* __restrict__ rb1,
                               const float* __restrict__ rw2,
                               const float* __restrict__ rb2,
                               float* __restrict__ routing) {
    const int b = blockIdx.x;
    const int t = threadIdx.x;
    __shared__ float pl[C_];
    __shared__ float part[256];
    __shared__ float hb[HID_];
    __shared__ float lg[E_];
    {   // reduce pool partials: 56 contiguous floats per thread
        const float* p = pp + (size_t)(b * C_ + t) * 56;
        float s = 0.f;
#pragma unroll
        for (int i = 0; i < 14; ++i) {
            float4 v = *(const float4*)(p + 4 * i);
            s += v.x + v.y + v.z + v.w;
        }
        pl[t] = s * (1.0f / (float)HW_);
    }
    __syncthreads();
    const int j = t >> 2, seg = t & 3;
    {
        const float* w = rw1 + j * C_ + seg * 64;
        const float* p = pl + seg * 64;
        float s = 0.0f;
#pragma unroll 8
        for (int cc = 0; cc < 64; ++cc) s += p[cc] * w[cc];
        part[t] = s;
    }
    __syncthreads();
    if (seg == 0) {
        float s = part[t] + part[t + 1] + part[t + 2] + part[t + 3] + rb1[j];
        hb[j] = fmaxf(s, 0.0f);
    }
    __syncthreads();
    if (t < E_) {
        float s = rb2[t];
        for (int jj = 0; jj < HID_; ++jj) s += hb[jj] * rw2[t * HID_ + jj];
        lg[t] = s;
    }
    __syncthreads();
    if (t == 0) {
        float mx = fmaxf(fmaxf(lg[0], lg[1]), fmaxf(lg[2], lg[3]));
        float e0 = expf(lg[0] - mx), e1 = expf(lg[1] - mx);
        float e2 = expf(lg[2] - mx), e3 = expf(lg[3] - mx);
        float inv = 1.0f / (e0 + e1 + e2 + e3);
        routing[b * E_ + 0] = e0 * inv;
        routing[b * E_ + 1] = e1 * inv;
        routing[b * E_ + 2] = e2 * inv;
        routing[b * E_ + 3] = e3 * inv;
    }
}

// --------------------- 3) combined weights, k = r*256+c ---------------------
// grid (256, 8): block (o, bg) handles b in [4*bg, 4*bg+4).
// Stores staged via LDS, written as uint4 (16 B/lane, fully coalesced).
__global__ void combine_kernel(const float* __restrict__ experts,
                               const float* __restrict__ routing,
                               unsigned short* __restrict__ wcomb) {
    const int o  = blockIdx.x;
    const int bg = blockIdx.y;
    const int c  = threadIdx.x;
    __shared__ alignas(16) unsigned short sh[KK_];
    __shared__ float rt[16];
    if (c < 16) rt[c] = routing[bg * 16 + c];

    float w[E_][9];
#pragma unroll
    for (int e = 0; e < E_; ++e) {
        const float* ep = experts + ((size_t)(e * O_ + o) * C_ + c) * 9;
        float4 v0 = *(const float4*)(ep + 0);
        float4 v1 = *(const float4*)(ep + 4);
        w[e][0] = v0.x; w[e][1] = v0.y; w[e][2] = v0.z; w[e][3] = v0.w;
        w[e][4] = v1.x; w[e][5] = v1.y; w[e][6] = v1.z; w[e][7] = v1.w;
        w[e][8] = ep[8];
    }
    __syncthreads();
#pragma unroll
    for (int bq = 0; bq < 4; ++bq) {
        const float r0 = rt[bq * 4 + 0], r1 = rt[bq * 4 + 1];
        const float r2 = rt[bq * 4 + 2], r3 = rt[bq * 4 + 3];
#pragma unroll
        for (int k = 0; k < 9; ++k) {
            float a = r0 * w[0][k] + r1 * w[1][k] + r2 * w[2][k] + r3 * w[3][k];
            sh[k * C_ + c] = f2bf(a);      // 2-way LDS bank alias: free
        }
        __syncthreads();
        const int b = bg * 4 + bq;
        uint4* dst = (uint4*)(wcomb + (size_t)(b * O_ + o) * KK_);
        const uint4* s4 = (const uint4*)sh;
        for (int idx = c; idx < KK_ / 8; idx += 256) dst[idx] = s4[idx];
        __syncthreads();
    }
}

// --------------------------- 4) implicit-GEMM conv --------------------------
// BK=64, XOR-swizzled LDS (conflict-free), XCD-clustered linear grid.
// __launch_bounds__(256,4): target VGPR+AGPR <= 128 for 4 blocks/CU.
__global__ __launch_bounds__(256, 4) void conv_gemm(const unsigned short* __restrict__ xp,
                                                    const unsigned short* __restrict__ wcomb,
                                                    float* __restrict__ out) {
    __shared__ alignas(16) unsigned short Alds[128 * 64];  // 16 KB
    __shared__ alignas(16) unsigned short Blds[128 * 64];  // 16 KB

    const int tid  = threadIdx.x;
    const int lane = tid & 63;
    const int wid  = tid >> 6;

    const int id = blockIdx.x;
    const int b  = (id >> 3) / 50 * 8 + (id & 7);   // all 50 tiles of b on one XCD
    const int t  = (id >> 3) % 50;
    const int o0 = (t & 1) * 128;
    const int n0 = (t >> 1) * 128;

    const int qg = (lane & 7) ^ ((lane >> 3) & 7);  // swizzled global chunk

    const unsigned short* aptr = wcomb
        + (size_t)(b * O_ + o0 + wid * 32 + (lane >> 3)) * KK_ + qg * 8;
    const unsigned short* bptr = xp + (size_t)b * PHW_ * C_ + qg * 8;
    unsigned int boff[4];
#pragma unroll
    for (int iss = 0; iss < 4; ++iss) {
        int p = n0 + wid * 32 + iss * 8 + (lane >> 3);
        if (p > HW_ - 1) p = HW_ - 1;
        boff[iss] = (unsigned int)((p / W_) * HP_ + (p % W_)) * C_;
    }
    unsigned short* aldst = (unsigned short*)Alds + (wid * 32) * 64;
    unsigned short* bldst = (unsigned short*)Blds + (wid * 32) * 64;

    f32x4 acc[4][4];
#pragma unroll
    for (int i = 0; i < 4; ++i)
#pragma unroll
        for (int j = 0; j < 4; ++j) acc[i][j] = (f32x4){0.f, 0.f, 0.f, 0.f};

    const int fm = lane & 15;
    const int fq = lane >> 4;
    const int wm = wid >> 1, wn = wid & 1;
    const int colk0 = ((0 + fq) ^ (fm & 7)) * 8;
    const int colk1 = ((4 + fq) ^ (fm & 7)) * 8;
    const unsigned short* ardb = (const unsigned short*)Alds + (wm * 64 + fm) * 64;
    const unsigned short* brdb = (const unsigned short*)Blds + (wn * 64 + fm) * 64;

    for (int kc = 0; kc < 36; ++kc) {
        const int r   = kc >> 2;
        const int duA = kc * 64;
        const int duB = ((r / 3) * HP_ + (r % 3)) * C_ + (kc & 3) * 64;
        __syncthreads();
#pragma unroll
        for (int iss = 0; iss < 4; ++iss) {
            load_lds16(aptr + (size_t)iss * (8 * KK_) + duA, aldst + iss * (8 * 64));
            load_lds16(bptr + boff[iss] + duB,              bldst + iss * (8 * 64));
        }
        __syncthreads();
#pragma unroll
        for (int ks = 0; ks < 2; ++ks) {
            const int col = ks ? colk1 : colk0;
            bf16x8 af[4], bv[4];
#pragma unroll
            for (int mi = 0; mi < 4; ++mi) af[mi] = *(const bf16x8*)(ardb + mi * (16 * 64) + col);
#pragma unroll
            for (int ni = 0; ni < 4; ++ni) bv[ni] = *(const bf16x8*)(brdb + ni * (16 * 64) + col);
#pragma unroll
            for (int mi = 0; mi < 4; ++mi)
#pragma unroll
                for (int ni = 0; ni < 4; ++ni)
                    acc[mi][ni] = __builtin_amdgcn_mfma_f32_16x16x32_bf16(
                        af[mi], bv[ni], acc[mi][ni], 0, 0, 0);
        }
    }

    // epilogue: D layout col(n)=lane&15, row(m)=(lane>>4)*4+reg
#pragma unroll
    for (int ni = 0; ni < 4; ++ni) {
        const int n = n0 + wn * 64 + ni * 16 + fm;
        if (n >= HW_) continue;
#pragma unroll
        for (int mi = 0; mi < 4; ++mi) {
            const int m = o0 + wm * 64 + mi * 16 + fq * 4;
            float* po = out + (size_t)(b * O_ + m) * HW_ + n;
#pragma unroll
            for (int rg = 0; rg < 4; ++rg) po[(size_t)rg * HW_] = acc[mi][ni][rg];
        }
    }
}

// ---------------------------------------------------------------------------
extern "C" void kernel_launch(void* const* d_in, const int* in_sizes, int n_in,
                              void* d_out, int out_size, void* d_ws, size_t ws_size,
                              hipStream_t stream) {
    const float* x       = (const float*)d_in[0];
    const float* experts = (const float*)d_in[1];
    const float* rw1     = (const float*)d_in[2];
    const float* rb1     = (const float*)d_in[3];
    const float* rw2     = (const float*)d_in[4];
    const float* rb2     = (const float*)d_in[5];
    float* out = (float*)d_out;

    const size_t XP_OFF = 0;                                   // 55,115,776 B
    const size_t WC_OFF = 55115776;                            // 37,748,736 B
    const size_t PP_OFF = WC_OFF + 37748736;                   // 32*256*56*4 = 1,835,008 B
    const size_t RT_OFF = PP_OFF + 1835008;                    // 512 B
    unsigned short* xp    = (unsigned short*)((char*)d_ws + XP_OFF);
    unsigned short* wcomb = (unsigned short*)((char*)d_ws + WC_OFF);
    float* pp      = (float*)((char*)d_ws + PP_OFF);
    float* routing = (float*)((char*)d_ws + RT_OFF);

    transform_pool<<<dim3(H_, 2, B_), dim3(256), 0, stream>>>(x, xp, pp);
    routing_kernel<<<dim3(B_), dim3(256), 0, stream>>>(pp, rw1, rb1, rw2, rb2, routing);
    combine_kernel<<<dim3(O_, 8), dim3(256), 0, stream>>>(experts, routing, wcomb);
    conv_gemm<<<dim3(1600), dim3(256), 0, stream>>>(xp, wcomb, out);
}